// Round 1
// baseline (3200.841 us; speedup 1.0000x reference)
//
#include <hip/hip_runtime.h>

// CharLSTM forward: B=16, T=256, H=1024, V=32000
// Phases:
//   P0 prep: fuse/transpose weights to bf16, embed gather, zero state
//   P1 Gx = emb @ Wx_fused + b  (MFMA GEMM, output layout [T][4H][B] for step-kernel reads)
//   P2 256 x lstm_step: g = Gx[t] + H@Wh; gate nonlinearities; C,H update; H_t -> Hs (bf16)
//   P3 Ys = Hs @ W_hq + b_q  (MFMA GEMM, output layout [B][T][V] f32 = d_out)
//   H,C f32 written to d_out tail at t=T-1.

typedef __bf16 bf16_t;
typedef bf16_t bf16x8 __attribute__((ext_vector_type(8)));
typedef float f32x4 __attribute__((ext_vector_type(4)));
typedef unsigned short u16;
typedef unsigned int u32;

#define B_ 16
#define T_ 256
#define H_ 1024
#define V_ 32000

__device__ __forceinline__ u16 f2bf(float x) {
  union { float f; u32 u; } v; v.f = x;
  u32 r = v.u + 0x7FFFu + ((v.u >> 16) & 1u);
  return (u16)(r >> 16);
}

__device__ __forceinline__ bf16x8 ldb8(const u16* p) {
  return *reinterpret_cast<const bf16x8*>(p);
}

// ---------------- prep kernels ----------------

__global__ void k_init(u16* Hs0, float* Cg) {
  int i = blockIdx.x * 256 + threadIdx.x;   // 64*256 = 16384 = B_*H_
  Hs0[i] = 0;
  Cg[i] = 0.0f;
}

// emb_bf16[t][b][h] = bf16(embedding[ids[b][t]][h]); grid 4096 blocks x 256 thr
__global__ void k_embed(const int* __restrict__ ids, const float* __restrict__ emb,
                        u16* __restrict__ out) {
  int r = blockIdx.x;               // r = t*16 + b
  int t = r >> 4, b = r & 15;
  int row = ids[b * T_ + t];
  const f32x4 v = *(const f32x4*)&emb[(size_t)row * H_ + threadIdx.x * 4];
  ushort4 o;
  o.x = f2bf(v[0]); o.y = f2bf(v[1]); o.z = f2bf(v[2]); o.w = f2bf(v[3]);
  *(ushort4*)&out[(size_t)r * H_ + threadIdx.x * 4] = o;
}

// WT[n][k] = bf16(W_{n>>10}[k][n&1023]); optional fused bias. grid 4096 x 256
__global__ void k_fuse(const float* __restrict__ W0, const float* __restrict__ W1,
                       const float* __restrict__ W2, const float* __restrict__ W3,
                       const float* b0, const float* b1, const float* b2, const float* b3,
                       u16* __restrict__ WT, float* bfused) {
  int n = blockIdx.x;
  int g = n >> 10, u = n & 1023;
  const float* W = (g == 0) ? W0 : (g == 1) ? W1 : (g == 2) ? W2 : W3;
  int k = threadIdx.x * 4;
  ushort4 o;
  o.x = f2bf(W[(size_t)(k + 0) * H_ + u]);
  o.y = f2bf(W[(size_t)(k + 1) * H_ + u]);
  o.z = f2bf(W[(size_t)(k + 2) * H_ + u]);
  o.w = f2bf(W[(size_t)(k + 3) * H_ + u]);
  *(ushort4*)&WT[(size_t)n * H_ + k] = o;
  if (threadIdx.x == 0 && bfused) {
    const float* bb = (g == 0) ? b0 : (g == 1) ? b1 : (g == 2) ? b2 : b3;
    bfused[n] = bb[u];
  }
}

// WqT[n][k] = bf16(Whq[k][n]) via LDS 64x64 tile transpose. grid (500, 16) x 256
__global__ void k_transq(const float* __restrict__ Whq, u16* __restrict__ WqT) {
  __shared__ float ti[64][65];
  int n0 = blockIdx.x * 64, k0 = blockIdx.y * 64;
  int c = threadIdx.x & 63, rq = threadIdx.x >> 6;  // rq 0..3
#pragma unroll
  for (int p = 0; p < 16; ++p) {
    int rr = p * 4 + rq;
    ti[rr][c] = Whq[(size_t)(k0 + rr) * V_ + n0 + c];
  }
  __syncthreads();
#pragma unroll
  for (int p = 0; p < 16; ++p) {
    int nn = p * 4 + rq;
    WqT[(size_t)(n0 + nn) * H_ + k0 + c] = f2bf(ti[c][nn]);
  }
}

// ---------------- MFMA GEMM (128x128 tile, 4 waves, reg-staged LDS) ----------------
// C = A[M][K] * Bt[N][K]^T + bias[n]
// MODE 0: out[((t*N + n)*16 + b], row r = t*16+b   -> Gx layout [T][4H][B]
// MODE 1: out[b*(T_*V_) + t*V_ + n]                -> Ys layout [B][T][V]
template <int MODE>
__global__ __launch_bounds__(256)
void gemm128(const u16* __restrict__ A, const u16* __restrict__ Bt,
             const float* __restrict__ bias, float* __restrict__ out,
             int M, int N, int K) {
  __shared__ u16 As[128 * 40];   // rows padded to 40 elems (80 B) -> low bank conflict
  __shared__ u16 Bs[128 * 40];
  const int tid = threadIdx.x;
  const int l = tid & 63, w = tid >> 6;
  const int m0 = blockIdx.y * 128, n0 = blockIdx.x * 128;
  const int wm = (w & 1) * 64, wn = (w >> 1) * 64;
  const int koff = (l >> 4) * 8;

  f32x4 acc[4][4] = {};

  for (int k0 = 0; k0 < K; k0 += 32) {
#pragma unroll
    for (int c = tid; c < 512; c += 256) {
      int mm = c >> 2, kk = (c & 3) * 8;
      *(uint4*)&As[mm * 40 + kk] = *(const uint4*)&A[(size_t)(m0 + mm) * K + k0 + kk];
      *(uint4*)&Bs[mm * 40 + kk] = *(const uint4*)&Bt[(size_t)(n0 + mm) * K + k0 + kk];
    }
    __syncthreads();
    bf16x8 af[4], bfr[4];
#pragma unroll
    for (int tm = 0; tm < 4; ++tm)
      af[tm] = ldb8(&As[(wm + tm * 16 + (l & 15)) * 40 + koff]);
#pragma unroll
    for (int tn = 0; tn < 4; ++tn)
      bfr[tn] = ldb8(&Bs[(wn + tn * 16 + (l & 15)) * 40 + koff]);
#pragma unroll
    for (int tm = 0; tm < 4; ++tm)
#pragma unroll
      for (int tn = 0; tn < 4; ++tn)
        acc[tm][tn] = __builtin_amdgcn_mfma_f32_16x16x32_bf16(af[tm], bfr[tn], acc[tm][tn], 0, 0, 0);
    __syncthreads();
  }

  // epilogue; D frag: col = l&15 (N), row = (l>>4)*4 + j (M)
#pragma unroll
  for (int tm = 0; tm < 4; ++tm) {
    int rbase = m0 + wm + tm * 16 + (l >> 4) * 4;
    int t = rbase >> 4;            // same for j=0..3 (rbase%16 <= 12)
    int bb = rbase & 15;
#pragma unroll
    for (int tn = 0; tn < 4; ++tn) {
      int n = n0 + wn + tn * 16 + (l & 15);
      float bv = bias[n];
      if (MODE == 0) {
        f32x4 v = acc[tm][tn];
        v[0] += bv; v[1] += bv; v[2] += bv; v[3] += bv;
        *(f32x4*)&out[((size_t)t * N + n) * 16 + bb] = v;
      } else {
#pragma unroll
        for (int j = 0; j < 4; ++j) {
          out[(size_t)(bb + j) * ((size_t)T_ * V_) + (size_t)t * V_ + n] = acc[tm][tn][j] + bv;
        }
      }
    }
  }
}

// ---------------- LSTM recurrence step ----------------
// grid 64 blocks x 256 thr = 256 waves; wave gw owns hidden units [gw*4, gw*4+4)
// computes g[16 batch][16 cols] = Hprev @ WhT-slice, adds Gx[t], applies gates.
__global__ __launch_bounds__(256)
void lstm_step(const u16* __restrict__ WhT, const u16* __restrict__ Hprev,
               const float* __restrict__ Gx_t,       // [4096][16]
               float* __restrict__ Cg, u16* __restrict__ Hnext,
               float* __restrict__ outH, float* __restrict__ outC, int last) {
  __shared__ float gx[4][16][16];
  const int tid = threadIdx.x, l = tid & 63, w = tid >> 6;
  const int gw = blockIdx.x * 4 + w;            // 0..255
  const int hu0 = gw * 4;
  const int c = l & 15;                          // local col: gate g = c>>2, unit u = c&3
  const int n = (c >> 2) * H_ + hu0 + (c & 3);   // fused gate column
  const int koff = (l >> 4) * 8;

  const u16* ap = Hprev + (size_t)(l & 15) * H_ + koff;
  const u16* bp = WhT + (size_t)n * H_ + koff;

  f32x4 acc = {0.f, 0.f, 0.f, 0.f};
#pragma unroll
  for (int kk = 0; kk < 32; ++kk) {
    bf16x8 a = ldb8(ap + kk * 32);
    bf16x8 b = ldb8(bp + kk * 32);
    acc = __builtin_amdgcn_mfma_f32_16x16x32_bf16(a, b, acc, 0, 0, 0);
  }

  const f32x4 g4 = *(const f32x4*)&Gx_t[(size_t)n * 16 + (l >> 4) * 4];
#pragma unroll
  for (int j = 0; j < 4; ++j)
    gx[w][(l >> 4) * 4 + j][c] = acc[j] + g4[j];
  __syncthreads();

  // lane -> (batch m, unit u)
  int m = l & 15, u = l >> 4, hu = hu0 + u;
  float gi = gx[w][m][0 + u];
  float gf = gx[w][m][4 + u];
  float go = gx[w][m][8 + u];
  float gc = gx[w][m][12 + u];
  float I = 1.0f / (1.0f + expf(-gi));
  float F = 1.0f / (1.0f + expf(-gf));
  float O = 1.0f / (1.0f + expf(-go));
  float Ct = tanhf(gc);
  size_t idx = (size_t)m * H_ + hu;
  float Cn = F * Cg[idx] + I * Ct;
  float Hn = O * tanhf(Cn);
  Cg[idx] = Cn;
  Hnext[idx] = f2bf(Hn);
  if (last) { outH[idx] = Hn; outC[idx] = Cn; }
}

// ---------------- host launcher ----------------

extern "C" void kernel_launch(void* const* d_in, const int* in_sizes, int n_in,
                              void* d_out, int out_size, void* d_ws, size_t ws_size,
                              hipStream_t stream) {
  const int*   ids = (const int*)d_in[0];
  const float* emb = (const float*)d_in[1];
  const float* Wxi = (const float*)d_in[2];
  const float* Whi = (const float*)d_in[3];
  const float* bi  = (const float*)d_in[4];
  const float* Wxf = (const float*)d_in[5];
  const float* Whf = (const float*)d_in[6];
  const float* bfv = (const float*)d_in[7];
  const float* Wxo = (const float*)d_in[8];
  const float* Who = (const float*)d_in[9];
  const float* bo  = (const float*)d_in[10];
  const float* Wxc = (const float*)d_in[11];
  const float* Whc = (const float*)d_in[12];
  const float* bc  = (const float*)d_in[13];
  const float* Whq = (const float*)d_in[14];
  const float* bq  = (const float*)d_in[15];
  float* out = (float*)d_out;

  char* ws = (char*)d_ws;
  u16* WxT = (u16*)ws;      ws += (size_t)4096 * H_ * 2;        // 8.4 MB
  u16* WhT = (u16*)ws;      ws += (size_t)4096 * H_ * 2;        // 8.4 MB
  u16* WqT = (u16*)ws;      ws += (size_t)V_ * H_ * 2;          // 65.5 MB
  u16* Emb = (u16*)ws;      ws += (size_t)T_ * B_ * H_ * 2;     // 8.4 MB
  float* Gx = (float*)ws;   ws += (size_t)T_ * 4096 * B_ * 4;   // 67 MB
  u16* Hs  = (u16*)ws;      ws += (size_t)(T_ + 1) * B_ * H_ * 2; // 8.4 MB
  float* Cg = (float*)ws;   ws += (size_t)B_ * H_ * 4;
  float* bfu = (float*)ws;  ws += (size_t)4096 * 4;

  // P0: prep
  k_init<<<64, 256, 0, stream>>>(Hs, Cg);
  k_embed<<<4096, 256, 0, stream>>>(ids, emb, Emb);
  k_fuse<<<4096, 256, 0, stream>>>(Wxi, Wxf, Wxo, Wxc, bi, bfv, bo, bc, WxT, bfu);
  k_fuse<<<4096, 256, 0, stream>>>(Whi, Whf, Who, Whc, nullptr, nullptr, nullptr, nullptr, WhT, nullptr);
  k_transq<<<dim3(500, 16), 256, 0, stream>>>(Whq, WqT);

  // P1: Gx = emb @ Wx + b   (M=4096, N=4096, K=1024)
  gemm128<0><<<dim3(32, 32), 256, 0, stream>>>(Emb, WxT, bfu, Gx, 4096, 4096, H_);

  // P2: recurrence
  float* outH = out + (size_t)B_ * T_ * V_;
  float* outC = outH + (size_t)B_ * H_;
  for (int t = 0; t < T_; ++t) {
    lstm_step<<<64, 256, 0, stream>>>(WhT,
                                      Hs + (size_t)t * B_ * H_,
                                      Gx + (size_t)t * 4096 * B_,
                                      Cg,
                                      Hs + (size_t)(t + 1) * B_ * H_,
                                      outH, outC, (t == T_ - 1) ? 1 : 0);
  }

  // P3: Ys = Hs[1..T] @ W_hq + b_q  (M=4096, N=32000, K=1024)
  gemm128<1><<<dim3(250, 32), 256, 0, stream>>>(Hs + (size_t)B_ * H_, WqT, bq, out, 4096, V_, H_);
}